// Round 14
// baseline (773.941 us; speedup 1.0000x reference)
//
#include <hip/hip_runtime.h>
#include <hip/hip_bf16.h>

// WMSA round 10: two-kernel split (QKV GEMM -> qkv intermediate -> attention+out-proj),
// with runtime fallback to the verified r13 fused kernel when ws_size is too small.
//  kA: per-window QKV GEMM; stores QKa[w][49][Q96|K96] and Va[w][96][64] (bf16).
//  kB: stages K/V^T from contiguous intermediate, Q direct to regs, swapped QK^T,
//      in-lane softmax, swapped PV -> O^T in regs, shuffle redistribution (r12-verified)
//      -> unswapped out-proj -> r13 store form. 2 barriers per kernel.

#define CH    96
#define MMTOK 49
#define HWD   224
#define PLANE (HWD * HWD)

typedef __attribute__((ext_vector_type(8))) __bf16 bfrag;
typedef __attribute__((ext_vector_type(4))) float  f4;
#define MFMA(a,b,c) __builtin_amdgcn_mfma_f32_16x16x32_bf16(a,b,c,0,0,0)

// ws layout: weights bf16 [0,73728); QKa at OFF_QKA; Va at OFF_VA (byte offsets)
#define WS_OW   27648
#define WS_TOT  36864
#define OFF_QKA 81920ull
#define OFF_VA  308363264ull            // 81920 + 16384*49*192*2
#define WS_NEED 509689856ull            // OFF_VA + 16384*96*64*2

// LDS pitches (bf16 elems)
#define PA_W  104   // kA s_win
#define PA_QK 200   // kA s_qk [64][Q 0..95 | K 96..191]
#define PA_V  72    // kA s_vT [96][64 tok + pad]
#define PB_K  104   // kB s_k [64][96+pad]
#define PB_V  72    // kB s_vT [96][64+pad]
#define PB_P  72    // kB per-wave P strip
// r13 fused-kernel pitches
#define PW_W  104
#define PW_V  72
#define PW_P  72

extern "C" __global__ void __launch_bounds__(256)
cvt_weights(const float* __restrict__ qw, const float* __restrict__ ow,
            __hip_bfloat16* __restrict__ ws)
{
    int i = blockIdx.x * 256 + threadIdx.x;
    if (i >= WS_TOT) return;
    ws[i] = __float2bfloat16(i < WS_OW ? qw[i] : ow[i - WS_OW]);
}

__device__ __forceinline__ unsigned packbf2(float lo, float hi) {
    union { __hip_bfloat16 h[2]; unsigned u; } p;
    p.h[0] = __float2bfloat16(lo);
    p.h[1] = __float2bfloat16(hi);
    return p.u;
}

// ===================== kernel A: QKV projection =====================
extern "C" __global__ void __launch_bounds__(256)
wmsa_qkv(const float* __restrict__ x,
         const __hip_bfloat16* __restrict__ ws,
         const float* __restrict__ qkvb,
         __hip_bfloat16* __restrict__ QKa,
         __hip_bfloat16* __restrict__ Va)
{
    __shared__ __align__(16) __hip_bfloat16 s_win[64 * PA_W];
    __shared__ __align__(16) __hip_bfloat16 s_qk [64 * PA_QK];
    __shared__ __align__(16) __hip_bfloat16 s_vT [96 * PA_V];

    const int tid  = threadIdx.x;
    const int cpx  = gridDim.x >> 3;
    const int wid  = (blockIdx.x & 7) * cpx + (blockIdx.x >> 3);
    const int b    = wid >> 10;
    const int w    = wid & 1023;
    const int h0   = (w >> 5) * 7;
    const int w0   = (w & 31) * 7;
    const int lane = tid & 63;
    const int wv   = tid >> 6;
    const int lr   = lane & 15;
    const int lg   = lane >> 4;
    const int trow = wv * 16 + lg * 4;

    const __hip_bfloat16* QW = ws;

    // window load (r13 pattern): t = lane, c = wv + 4k
    {
        const int t  = lane;
        const int tt = (t < MMTOK) ? t : 0;
        const int ti = tt / 7, tj = tt - ti * 7;
        const float* xp = x + ((size_t)(b * CH + wv) * PLANE)
                            + (size_t)(h0 + ti) * HWD + (w0 + tj);
        float rx[24];
        #pragma unroll
        for (int k = 0; k < 24; ++k)
            rx[k] = xp[(size_t)k * 4 * PLANE];
        const float zm = (t < MMTOK) ? 1.f : 0.f;
        #pragma unroll
        for (int k = 0; k < 24; ++k)
            s_win[t * PA_W + wv + 4 * k] = __float2bfloat16(rx[k] * zm);
    }
    __syncthreads();                                   // [1]

    bfrag aq[3];
    #pragma unroll
    for (int k = 0; k < 3; ++k)
        aq[k] = *(const bfrag*)&s_win[(wv * 16 + lr) * PA_W + k * 32 + lg * 8];

    #pragma unroll
    for (int ob = 0; ob < 3; ++ob) {
        const __hip_bfloat16* QWrow = QW + (ob * 96 + lr) * 96 + lg * 8;
        f4 acc[6];
        #pragma unroll
        for (int n = 0; n < 6; ++n) {
            float bb = qkvb[ob * 96 + n * 16 + lr];
            acc[n] = f4{bb, bb, bb, bb};
        }
        bfrag b0[6], b1[6];
        #pragma unroll
        for (int n = 0; n < 6; ++n) b0[n] = *(const bfrag*)&QWrow[n * 16 * 96 + 0 * 32];
        #pragma unroll
        for (int n = 0; n < 6; ++n) b1[n] = *(const bfrag*)&QWrow[n * 16 * 96 + 1 * 32];
        __builtin_amdgcn_s_setprio(1);
        #pragma unroll
        for (int n = 0; n < 6; ++n) acc[n] = MFMA(aq[0], b0[n], acc[n]);
        __builtin_amdgcn_s_setprio(0);
        #pragma unroll
        for (int n = 0; n < 6; ++n) b0[n] = *(const bfrag*)&QWrow[n * 16 * 96 + 2 * 32];
        __builtin_amdgcn_s_setprio(1);
        #pragma unroll
        for (int n = 0; n < 6; ++n) acc[n] = MFMA(aq[1], b1[n], acc[n]);
        #pragma unroll
        for (int n = 0; n < 6; ++n) acc[n] = MFMA(aq[2], b0[n], acc[n]);
        __builtin_amdgcn_s_setprio(0);

        // C-store: Q -> s_qk[t][ob*32+d]; K -> s_qk[t][96+ob*32+d]; V^T -> s_vT
        #pragma unroll
        for (int n = 0; n < 6; ++n) {
            int part = n >> 1;
            int d = ((n & 1) << 4) + lr;
            #pragma unroll
            for (int r = 0; r < 4; ++r) {
                __hip_bfloat16 hv = __float2bfloat16(acc[n][r]);
                int tk = trow + r;
                if (part == 0)      s_qk[tk * PA_QK + ob * 32 + d] = hv;
                else if (part == 1) s_qk[tk * PA_QK + 96 + ob * 32 + d] = hv;
                else                s_vT[(ob * 32 + d) * PA_V + tk] = hv;
            }
        }
    }
    __syncthreads();                                   // [2]

    // cooperative stores: QKa [49][192], Va [96][64]
    for (int idx = tid; idx < 49 * 24; idx += 256) {
        int t = idx / 24, c8 = (idx - t * 24) * 8;
        *(uint4*)&QKa[((size_t)wid * 49 + t) * 192 + c8] =
            *(const uint4*)&s_qk[t * PA_QK + c8];
    }
    for (int idx = tid; idx < 96 * 8; idx += 256) {
        int d = idx / 8, c8 = (idx - d * 8) * 8;
        *(uint4*)&Va[((size_t)wid * 96 + d) * 64 + c8] =
            *(const uint4*)&s_vT[d * PA_V + c8];
    }
}

// ===================== kernel B: attention + out-proj =====================
extern "C" __global__ void __launch_bounds__(256, 4)
wmsa_attn(const __hip_bfloat16* __restrict__ QKa,
          const __hip_bfloat16* __restrict__ Va,
          const __hip_bfloat16* __restrict__ ws,     // OW at +WS_OW
          const float* __restrict__ bt,
          const float* __restrict__ outb,
          float* __restrict__ out)
{
    __shared__ __align__(16) __hip_bfloat16 s_k [64 * PB_K];
    __shared__ __align__(16) __hip_bfloat16 s_vT[96 * PB_V];
    __shared__ __align__(16) __hip_bfloat16 s_P [4][16 * PB_P];
    __shared__ float s_bias[507];

    const int tid  = threadIdx.x;
    const int cpx  = gridDim.x >> 3;
    const int wid  = (blockIdx.x & 7) * cpx + (blockIdx.x >> 3);
    const int b    = wid >> 10;
    const int w    = wid & 1023;
    const int lane = tid & 63;
    const int wv   = tid >> 6;
    const int lr   = lane & 15;
    const int lg   = lane >> 4;
    const int trow = wv * 16 + lg * 4;

    const __hip_bfloat16* OW = ws + WS_OW;

    // early Q loads (own query row p = wv*16+lr), clamped
    const int p    = wv * 16 + lr;
    const bool pok = (p < MMTOK);
    const int pp   = pok ? p : 48;
    bfrag qf[3];
    {
        const __hip_bfloat16* qrow = QKa + ((size_t)wid * 49 + pp) * 192 + lg * 8;
        #pragma unroll
        for (int h = 0; h < 3; ++h)
            qf[h] = *(const bfrag*)&qrow[h * 32];
    }

    // stage bias
    for (int i = tid; i < 507; i += 256) s_bias[i] = bt[i];
    // stage K (zero rows >=49)
    for (int idx = tid; idx < 64 * 12; idx += 256) {
        int t = idx / 12, c8 = (idx - t * 12) * 8;
        uint4 v = {0, 0, 0, 0};
        if (t < MMTOK)
            v = *(const uint4*)&QKa[((size_t)wid * 49 + t) * 192 + 96 + c8];
        *(uint4*)&s_k[t * PB_K + c8] = v;
    }
    // stage V^T (cols >=49 hold finite bias values from kA; P=0 masks them)
    for (int idx = tid; idx < 96 * 8; idx += 256) {
        int d = idx / 8, c8 = (idx - d * 8) * 8;
        *(uint4*)&s_vT[d * PB_V + c8] = *(const uint4*)&Va[((size_t)wid * 96 + d) * 64 + c8];
    }
    __syncthreads();                                   // [1]

    // bias indices (r13)
    const int a1p = ((pp / 7) * 13 + (pp % 7)) * 3 + 252;
    int bidx[16];
    #pragma unroll
    for (int m = 0; m < 4; ++m)
        #pragma unroll
        for (int r = 0; r < 4; ++r) {
            int kt = m * 16 + lg * 4 + r;
            int kc = (kt < MMTOK) ? kt : 48;
            bidx[m * 4 + r] = a1p - ((kc / 7) * 13 + (kc % 7)) * 3;
        }

    const float inv_scale = 0.0180421959f;             // sqrt(3)/96
    unsigned pk2[6][2];                                 // O^T bf16 pairs

    #pragma unroll
    for (int h = 0; h < 3; ++h) {
        // swapped QK^T
        f4 sc[4];
        __builtin_amdgcn_s_setprio(1);
        #pragma unroll
        for (int m = 0; m < 4; ++m) {
            bfrag kf = *(const bfrag*)&s_k[(m * 16 + lr) * PB_K + h * 32 + lg * 8];
            f4 z = f4{0.f, 0.f, 0.f, 0.f};
            sc[m] = MFMA(kf, qf[h], z);
        }
        __builtin_amdgcn_s_setprio(0);

        // in-lane softmax (r13)
        float val[16];
        #pragma unroll
        for (int m = 0; m < 4; ++m)
            #pragma unroll
            for (int r = 0; r < 4; ++r)
                val[m * 4 + r] = fmaf(sc[m][r], inv_scale, s_bias[bidx[m * 4 + r] + h]);
        float mx = fmaxf(fmaxf(fmaxf(val[0], val[1]), fmaxf(val[2], val[3])),
                   fmaxf(fmaxf(fmaxf(val[4], val[5]), fmaxf(val[6], val[7])),
                   fmaxf(fmaxf(fmaxf(val[8], val[9]), fmaxf(val[10], val[11])),
                         fmaxf(fmaxf(val[12], val[13]), fmaxf(val[14], val[15])))));
        mx = fmaxf(mx, __shfl_xor(mx, 16));
        mx = fmaxf(mx, __shfl_xor(mx, 32));
        float sum = 0.f;
        #pragma unroll
        for (int m = 0; m < 4; ++m)
            #pragma unroll
            for (int r = 0; r < 4; ++r) {
                int i = m * 4 + r;
                float e = __expf(val[i] - mx);
                e = (m * 16 + lg * 4 + r < MMTOK) ? e : 0.f;
                val[i] = e;
                sum += e;
            }
        sum += __shfl_xor(sum, 16);
        sum += __shfl_xor(sum, 32);
        const float inv = pok ? (1.0f / sum) : 0.f;

        #pragma unroll
        for (int m = 0; m < 4; ++m) {
            union { __hip_bfloat16 hh[4]; uint2 u; } pk;
            #pragma unroll
            for (int r = 0; r < 4; ++r) pk.hh[r] = __float2bfloat16(val[m * 4 + r] * inv);
            *(uint2*)&s_P[wv][lr * PB_P + m * 16 + lg * 4] = pk.u;
        }
        // same-wave RAW on s_P

        // swapped PV -> O^T in regs (r12-verified)
        bfrag pa0 = *(const bfrag*)&s_P[wv][lr * PB_P + 0 * 32 + lg * 8];
        bfrag pa1 = *(const bfrag*)&s_P[wv][lr * PB_P + 1 * 32 + lg * 8];
        __builtin_amdgcn_s_setprio(1);
        #pragma unroll
        for (int nblk = 0; nblk < 2; ++nblk) {
            bfrag vb0 = *(const bfrag*)&s_vT[(h * 32 + nblk * 16 + lr) * PB_V + 0 * 32 + lg * 8];
            bfrag vb1 = *(const bfrag*)&s_vT[(h * 32 + nblk * 16 + lr) * PB_V + 1 * 32 + lg * 8];
            f4 oc = f4{0.f, 0.f, 0.f, 0.f};
            oc = MFMA(vb0, pa0, oc);     // A = V^T, B = P^T -> D = O^T
            oc = MFMA(vb1, pa1, oc);
            pk2[h * 2 + nblk][0] = packbf2(oc[0], oc[1]);
            pk2[h * 2 + nblk][1] = packbf2(oc[2], oc[3]);
        }
        __builtin_amdgcn_s_setprio(0);
    }

    // out-proj: shuffle redistribution (r12-verified) -> A-frags (stack rows)
    f4 yac[6];
    #pragma unroll
    for (int n = 0; n < 6; ++n) {
        float bb = outb[n * 16 + lr];
        yac[n] = f4{bb, bb, bb, bb};
    }
    const int sA = lr + 16 * (2 * (lg & 1));
    const bool hi = ((lg >> 1) & 1) != 0;
    #pragma unroll
    for (int kb = 0; kb < 3; ++kb) {
        unsigned A00 = __shfl(pk2[2 * kb + 0][0], sA);
        unsigned A01 = __shfl(pk2[2 * kb + 0][1], sA);
        unsigned A10 = __shfl(pk2[2 * kb + 1][0], sA);
        unsigned A11 = __shfl(pk2[2 * kb + 1][1], sA);
        unsigned B00 = __shfl(pk2[2 * kb + 0][0], sA + 16);
        unsigned B01 = __shfl(pk2[2 * kb + 0][1], sA + 16);
        unsigned B10 = __shfl(pk2[2 * kb + 1][0], sA + 16);
        unsigned B11 = __shfl(pk2[2 * kb + 1][1], sA + 16);
        union { unsigned w4[4]; bfrag v; } sb;
        sb.w4[0] = hi ? A10 : A00;
        sb.w4[1] = hi ? A11 : A01;
        sb.w4[2] = hi ? B10 : B00;
        sb.w4[3] = hi ? B11 : B01;
        __builtin_amdgcn_s_setprio(1);
        #pragma unroll
        for (int n = 0; n < 6; ++n) {
            bfrag wb = *(const bfrag*)&OW[(n * 16 + lr) * 96 + kb * 32 + lg * 8];
            yac[n] = MFMA(sb.v, wb, yac[n]);   // A = stack rows -> D[t][o]
        }
        __builtin_amdgcn_s_setprio(0);
    }

    __syncthreads();                                   // [2] store convergence

    // store (r13 form): flat = w*49 + t
    #pragma unroll
    for (int n = 0; n < 6; ++n) {
        int o = n * 16 + lr;
        #pragma unroll
        for (int r = 0; r < 4; ++r) {
            int t = trow + r;
            if (t < MMTOK) {
                int flat = w * MMTOK + t;
                int ho = flat / HWD, wo = flat - ho * HWD;
                out[((b * CH + o) * HWD + ho) * HWD + wo] = yac[n][r];
            }
        }
    }
}

// ===================== fallback: r13 fused kernel (verbatim) =====================
extern "C" __global__ void __launch_bounds__(256, 3)
wmsa_mfma(const float* __restrict__ x,
          const __hip_bfloat16* __restrict__ ws,
          const float* __restrict__ qkvb,
          const float* __restrict__ bt,
          const float* __restrict__ outb,
          float* __restrict__ out)
{
    __shared__ __align__(16) __hip_bfloat16 s_win[64 * PW_W];
    __shared__ __align__(16) __hip_bfloat16 s_k  [64 * PW_W];
    __shared__ __align__(16) __hip_bfloat16 s_vT [96 * PW_V];
    __shared__ __align__(16) __hip_bfloat16 s_P  [4][16 * PW_P];
    __shared__ float s_bias[507];

    const int tid  = threadIdx.x;
    const int cpx  = gridDim.x >> 3;
    const int wid  = (blockIdx.x & 7) * cpx + (blockIdx.x >> 3);
    const int b    = wid >> 10;
    const int w    = wid & 1023;
    const int h0   = (w >> 5) * 7;
    const int w0   = (w & 31) * 7;
    const int lane = tid & 63;
    const int wv   = tid >> 6;
    const int lr   = lane & 15;
    const int lg   = lane >> 4;
    const int trow = wv * 16 + lg * 4;

    const __hip_bfloat16* QW = ws;
    const __hip_bfloat16* OW = ws + WS_OW;

    for (int i = tid; i < 507; i += 256) s_bias[i] = bt[i];

    {
        const int t  = lane;
        const int tt = (t < MMTOK) ? t : 0;
        const int ti = tt / 7, tj = tt - ti * 7;
        const float* xp = x + ((size_t)(b * CH + wv) * PLANE)
                            + (size_t)(h0 + ti) * HWD + (w0 + tj);
        float rx[24];
        #pragma unroll
        for (int k = 0; k < 24; ++k) rx[k] = xp[(size_t)k * 4 * PLANE];
        const float zm = (t < MMTOK) ? 1.f : 0.f;
        #pragma unroll
        for (int k = 0; k < 24; ++k)
            s_win[t * PW_W + wv + 4 * k] = __float2bfloat16(rx[k] * zm);
    }
    __syncthreads();

    bfrag aq[3];
    #pragma unroll
    for (int k = 0; k < 3; ++k)
        aq[k] = *(const bfrag*)&s_win[(wv * 16 + lr) * PW_W + k * 32 + lg * 8];
    __syncthreads();

    const int p   = wv * 16 + lr;
    const bool pok = (p < MMTOK);
    const int pp  = pok ? p : 48;
    const int a1p = ((pp / 7) * 13 + (pp % 7)) * 3 + 252;
    int bidx[16];
    #pragma unroll
    for (int m = 0; m < 4; ++m)
        #pragma unroll
        for (int r = 0; r < 4; ++r) {
            int kt = m * 16 + lg * 4 + r;
            int kc = (kt < MMTOK) ? kt : 48;
            bidx[m * 4 + r] = a1p - ((kc / 7) * 13 + (kc % 7)) * 3;
        }

    const float inv_scale = 0.0180421959f;

    #pragma unroll
    for (int ob = 0; ob < 3; ++ob) {
        const __hip_bfloat16* QWrow = QW + (ob * 96 + lr) * 96 + lg * 8;
        f4 acc[6];
        #pragma unroll
        for (int n = 0; n < 6; ++n) {
            float bb = qkvb[ob * 96 + n * 16 + lr];
            acc[n] = f4{bb, bb, bb, bb};
        }
        bfrag b0[6], b1[6];
        #pragma unroll
        for (int n = 0; n < 6; ++n) b0[n] = *(const bfrag*)&QWrow[n * 16 * 96 + 0 * 32];
        #pragma unroll
        for (int n = 0; n < 6; ++n) b1[n] = *(const bfrag*)&QWrow[n * 16 * 96 + 1 * 32];
        __builtin_amdgcn_s_setprio(1);
        #pragma unroll
        for (int n = 0; n < 6; ++n) acc[n] = MFMA(aq[0], b0[n], acc[n]);
        __builtin_amdgcn_s_setprio(0);
        #pragma unroll
        for (int n = 0; n < 6; ++n) b0[n] = *(const bfrag*)&QWrow[n * 16 * 96 + 2 * 32];
        __builtin_amdgcn_s_setprio(1);
        #pragma unroll
        for (int n = 0; n < 6; ++n) acc[n] = MFMA(aq[1], b1[n], acc[n]);
        #pragma unroll
        for (int n = 0; n < 6; ++n) acc[n] = MFMA(aq[2], b0[n], acc[n]);
        __builtin_amdgcn_s_setprio(0);

        #pragma unroll
        for (int n = 0; n < 6; ++n) {
            int part = n >> 1;
            int d = ((n & 1) << 4) + lr;
            #pragma unroll
            for (int r = 0; r < 4; ++r) {
                __hip_bfloat16 hv = __float2bfloat16(acc[n][r]);
                int tk = trow + r;
                if (part == 0)      s_win[tk * PW_W + ob * 32 + d] = hv;
                else if (part == 1) s_k[tk * PW_W + ob * 32 + d] = hv;
                else                s_vT[(ob * 32 + d) * PW_V + tk] = hv;
            }
        }
    }
    __syncthreads();

    #pragma unroll
    for (int h = 0; h < 3; ++h) {
        bfrag qf = *(const bfrag*)&s_win[(wv * 16 + lr) * PW_W + h * 32 + lg * 8];
        f4 sc[4];
        __builtin_amdgcn_s_setprio(1);
        #pragma unroll
        for (int m = 0; m < 4; ++m) {
            bfrag kf = *(const bfrag*)&s_k[(m * 16 + lr) * PW_W + h * 32 + lg * 8];
            f4 z = f4{0.f, 0.f, 0.f, 0.f};
            sc[m] = MFMA(kf, qf, z);
        }
        __builtin_amdgcn_s_setprio(0);

        float val[16];
        #pragma unroll
        for (int m = 0; m < 4; ++m)
            #pragma unroll
            for (int r = 0; r < 4; ++r)
                val[m * 4 + r] = fmaf(sc[m][r], inv_scale, s_bias[bidx[m * 4 + r] + h]);
        float mx = fmaxf(fmaxf(fmaxf(val[0], val[1]), fmaxf(val[2], val[3])),
                   fmaxf(fmaxf(fmaxf(val[4], val[5]), fmaxf(val[6], val[7])),
                   fmaxf(fmaxf(fmaxf(val[8], val[9]), fmaxf(val[10], val[11])),
                         fmaxf(fmaxf(val[12], val[13]), fmaxf(val[14], val[15])))));
        mx = fmaxf(mx, __shfl_xor(mx, 16));
        mx = fmaxf(mx, __shfl_xor(mx, 32));
        float sum = 0.f;
        #pragma unroll
        for (int m = 0; m < 4; ++m)
            #pragma unroll
            for (int r = 0; r < 4; ++r) {
                int i = m * 4 + r;
                float e = __expf(val[i] - mx);
                e = (m * 16 + lg * 4 + r < MMTOK) ? e : 0.f;
                val[i] = e;
                sum += e;
            }
        sum += __shfl_xor(sum, 16);
        sum += __shfl_xor(sum, 32);
        const float inv = pok ? (1.0f / sum) : 0.f;

        #pragma unroll
        for (int m = 0; m < 4; ++m) {
            union { __hip_bfloat16 hh[4]; uint2 u; } pk;
            #pragma unroll
            for (int r = 0; r < 4; ++r) pk.hh[r] = __float2bfloat16(val[m * 4 + r] * inv);
            *(uint2*)&s_P[wv][lr * PW_P + m * 16 + lg * 4] = pk.u;
        }

        bfrag pa0 = *(const bfrag*)&s_P[wv][lr * PW_P + 0 * 32 + lg * 8];
        bfrag pa1 = *(const bfrag*)&s_P[wv][lr * PW_P + 1 * 32 + lg * 8];
        __builtin_amdgcn_s_setprio(1);
        #pragma unroll
        for (int n = 0; n < 2; ++n) {
            bfrag vb0 = *(const bfrag*)&s_vT[(h * 32 + n * 16 + lr) * PW_V + 0 * 32 + lg * 8];
            bfrag vb1 = *(const bfrag*)&s_vT[(h * 32 + n * 16 + lr) * PW_V + 1 * 32 + lg * 8];
            f4 oc = f4{0.f, 0.f, 0.f, 0.f};
            oc = MFMA(pa0, vb0, oc);
            oc = MFMA(pa1, vb1, oc);
            #pragma unroll
            for (int r = 0; r < 4; ++r)
                s_win[(trow + r) * PW_W + h * 32 + n * 16 + lr] = __float2bfloat16(oc[r]);
        }
        __builtin_amdgcn_s_setprio(0);
    }

    bfrag sa[3];
    #pragma unroll
    for (int k = 0; k < 3; ++k)
        sa[k] = *(const bfrag*)&s_win[(wv * 16 + lr) * PW_W + k * 32 + lg * 8];
    f4 yac[6];
    #pragma unroll
    for (int n = 0; n < 6; ++n) {
        float bb = outb[n * 16 + lr];
        yac[n] = f4{bb, bb, bb, bb};
    }
    {
        const __hip_bfloat16* OWrow = OW + lr * 96 + lg * 8;
        bfrag c0[6], c1[6];
        #pragma unroll
        for (int n = 0; n < 6; ++n) c0[n] = *(const bfrag*)&OWrow[n * 16 * 96 + 0 * 32];
        #pragma unroll
        for (int n = 0; n < 6; ++n) c1[n] = *(const bfrag*)&OWrow[n * 16 * 96 + 1 * 32];
        __builtin_amdgcn_s_setprio(1);
        #pragma unroll
        for (int n = 0; n < 6; ++n) yac[n] = MFMA(sa[0], c0[n], yac[n]);
        __builtin_amdgcn_s_setprio(0);
        #pragma unroll
        for (int n = 0; n < 6; ++n) c0[n] = *(const bfrag*)&OWrow[n * 16 * 96 + 2 * 32];
        __builtin_amdgcn_s_setprio(1);
        #pragma unroll
        for (int n = 0; n < 6; ++n) yac[n] = MFMA(sa[1], c1[n], yac[n]);
        #pragma unroll
        for (int n = 0; n < 6; ++n) yac[n] = MFMA(sa[2], c0[n], yac[n]);
        __builtin_amdgcn_s_setprio(0);
    }

    __syncthreads();

    #pragma unroll
    for (int n = 0; n < 6; ++n) {
        int o = n * 16 + lr;
        #pragma unroll
        for (int r = 0; r < 4; ++r) {
            int t = trow + r;
            if (t < MMTOK) {
                int flat = w * MMTOK + t;
                int ho = flat / HWD, wo = flat - ho * HWD;
                out[((b * CH + o) * HWD + ho) * HWD + wo] = yac[n][r];
            }
        }
    }
}

extern "C" void kernel_launch(void* const* d_in, const int* in_sizes, int n_in,
                              void* d_out, int out_size, void* d_ws, size_t ws_size,
                              hipStream_t stream) {
    const float* x  = (const float*)d_in[0];
    const float* qw = (const float*)d_in[1];
    const float* qb = (const float*)d_in[2];
    const float* bt = (const float*)d_in[3];
    const float* ow = (const float*)d_in[4];
    const float* ob = (const float*)d_in[5];
    float* out      = (float*)d_out;
    char* wsc       = (char*)d_ws;
    __hip_bfloat16* ws = (__hip_bfloat16*)wsc;

    cvt_weights<<<(WS_TOT + 255) / 256, 256, 0, stream>>>(qw, ow, ws);

    int B = in_sizes[0] / (CH * HWD * HWD);      // 16
    int nblocks = B * 1024;                      // 16384, %8==0

    if (ws_size >= WS_NEED) {
        __hip_bfloat16* QKa = (__hip_bfloat16*)(wsc + OFF_QKA);
        __hip_bfloat16* Va  = (__hip_bfloat16*)(wsc + OFF_VA);
        wmsa_qkv <<<nblocks, 256, 0, stream>>>(x, ws, qb, QKa, Va);
        wmsa_attn<<<nblocks, 256, 0, stream>>>(QKa, Va, ws, bt, ob, out);
    } else {
        wmsa_mfma<<<nblocks, 256, 0, stream>>>(x, ws, qb, bt, ob, out);
    }
}